// Round 4
// baseline (760.472 us; speedup 1.0000x reference)
//
#include <hip/hip_runtime.h>

typedef __attribute__((ext_vector_type(8))) short bf16x8;   // 8 bf16 = 4 VGPRs (MFMA A/B frag)
typedef __attribute__((ext_vector_type(4))) float f32x4;    // MFMA C/D frag
typedef __attribute__((ext_vector_type(4))) float f4;
typedef __attribute__((ext_vector_type(2))) unsigned int u32x2;
typedef __attribute__((ext_vector_type(4))) unsigned int u32x4;

#define HW   16384   // 128*128
#define FDIM 512

// pack bf16(trunc) of a (low 16) and b (high 16) in one v_perm_b32
__device__ __forceinline__ unsigned pkhi(float a, float b) {
    return __builtin_amdgcn_perm(__builtin_bit_cast(unsigned int, b),
                                 __builtin_bit_cast(unsigned int, a),
                                 0x07060302u);
}
__device__ __forceinline__ float trhi(float a) {
    return __builtin_bit_cast(float, __builtin_bit_cast(unsigned int, a) & 0xFFFF0000u);
}
__device__ __forceinline__ unsigned pklo(float a, float b) {
    return pkhi(a - trhi(a), b - trhi(b));
}

// ---------------------------------------------------------------------------
// Prologue 1: convert W[e,c,f] fp32 -> bf16 hi/lo in d_ws, n-reordered
// (n=c*16+e), MFMA B-frag order: W'[kchunk 0..63][n 0..1023][8 bf16].
__global__ __launch_bounds__(256) void conv_w(const float* __restrict__ wts,
                                              unsigned short* __restrict__ wh,
                                              unsigned short* __restrict__ wl) {
    const int tid = blockIdx.x * 256 + threadIdx.x;   // 65536 threads
    const int n  = tid & 1023;
    const int kc = tid >> 10;                         // k-chunk 0..63
    const float* src = wts + (size_t)((n & 15) * 64 + (n >> 4)) * FDIM + kc * 8;
    f4 a = *(const f4*)src, b = *(const f4*)(src + 4);
    u32x4 h = { pkhi(a[0], a[1]), pkhi(a[2], a[3]), pkhi(b[0], b[1]), pkhi(b[2], b[3]) };
    u32x4 l = { pklo(a[0], a[1]), pklo(a[2], a[3]), pklo(b[0], b[1]), pklo(b[2], b[3]) };
    size_t off = ((size_t)kc * 1024 + n) * 8;
    *(u32x4*)(wh + off) = h;    // 16 B per thread, consecutive n -> coalesced
    *(u32x4*)(wl + off) = l;
}

// ---------------------------------------------------------------------------
// Prologue 2 (R4): convert feat fp32 -> bf16 hi/lo A-frags ONCE.
// A'[bidx 0..7][kc 0..63][pixel 0..16383][8 bf16], element (b,kc,p,j) =
// feat[b][kc*8+j][p].  R3 evidence: the in-loop pack (16 perm + 16 perm +
// 32 and + 32 sub per kt per thread) made VALUBusy 48% ~= MfmaUtil 42% --
// the pack was recomputed 8x (per nb-sibling) on the critical path. Hoisting
// it here makes the main kernel's A-load ONE dwordx4 per frag, zero pack.
// Pack pairing identical to R3's step() -> bit-identical numerics.
__global__ __launch_bounds__(256) void conv_a(const float* __restrict__ feat,
                                              unsigned short* __restrict__ ah,
                                              unsigned short* __restrict__ al) {
    const size_t tid = (size_t)blockIdx.x * 256 + threadIdx.x;  // 8*64*16384
    const int p    = (int)(tid & (HW - 1));
    const int kc   = (int)((tid >> 14) & 63);
    const int bidx = (int)(tid >> 20);
    const float* src = feat + ((size_t)bidx * FDIM + (size_t)kc * 8) * HW + p;
    float a[8];
    #pragma unroll
    for (int j = 0; j < 8; ++j) a[j] = src[(size_t)j * HW];   // 64 lanes consecutive p: 256B segments
    u32x4 h = { pkhi(a[0], a[1]), pkhi(a[2], a[3]), pkhi(a[4], a[5]), pkhi(a[6], a[7]) };
    u32x4 l = { pklo(a[0], a[1]), pklo(a[2], a[3]), pklo(a[4], a[5]), pklo(a[6], a[7]) };
    size_t off = tid * 8;
    *(u32x4*)(ah + off) = h;    // fully coalesced 16B/thread
    *(u32x4*)(al + off) = l;
}

// ---------------------------------------------------------------------------
// Main (R4, big-ws tier): no LDS, no barriers (proven R3), and now no pack:
// A-frags load directly as dwordx4 from A' (L2-hot via XCD swizzle), B-frags
// from W'.  Per kt per thread: 8 A-loads + 8 B-loads + 48 MFMA + ~10 VALU.
__global__ __launch_bounds__(256, 2) void duq_pre(
    const unsigned short* __restrict__ ah,   // [8][64][16384][8] bf16 hi
    const unsigned short* __restrict__ al,   // bf16 lo
    const unsigned short* __restrict__ wh,   // [64][1024][8] bf16 hi
    const unsigned short* __restrict__ wl,   // bf16 lo
    const float* __restrict__ m_in,          // [16,64]
    const float* __restrict__ n_in,          // [64]
    float* __restrict__ out)                 // [8,64,128,128]
{
    const int t  = threadIdx.x;
    const int bx = blockIdx.x;
    // XCD swizzle (proven R2): (bx&7) = XCD id; each XCD owns a contiguous mb
    // range, 8 nb-siblings dispatch-adjacent -> A panel L2-resident per XCD.
    const int kb = bx >> 3;
    const int nb = kb & 7;                    // N block: 1024/128
    const int mb = (bx & 7) * 128 + (kb >> 3);
    const int bidx = mb >> 7;
    const int hw0  = (mb & 127) << 7;

    const int lane = t & 63;
    const int wv = t >> 6;
    const int wm = wv >> 1, wn = wv & 1;      // 2x2 waves, 64x64 each
    const int l16 = lane & 15, qd = lane >> 4;

    // A-frag base: lane (l16,qd) of wave wm, frag i -> pixel hw0+wm*64+l16+i*16,
    // kc = kt*4 + qd.  16 lanes x 16B consecutive = 256B coalesced per i.
    const size_t a0 = ((size_t)(bidx * 64 + qd) * HW + (size_t)(hw0 + wm * 64 + l16)) * 8;
    const unsigned short* agh = ah + a0;
    const unsigned short* agl = al + a0;

    // B frag base: frag (kt,j) is 16 B at bgh + kt*32768 + j*128
    const size_t bgoff = ((size_t)qd * 1024 + (size_t)(nb * 128 + wn * 64 + l16)) * 8;
    const unsigned short* bgh = wh + bgoff;
    const unsigned short* bgl = wl + bgoff;

    f32x4 acc[4][4] = {};

    // preload B-frag (kt=0, j=0)
    bf16x8 cbh = *(const bf16x8*)(bgh);
    bf16x8 cbl = *(const bf16x8*)(bgl);
    size_t boff = 0;

    // load one kt's A frags (4 x hi + 4 x lo dwordx4), advance 4 kc
    auto ldA = [&](bf16x8 (&dh)[4], bf16x8 (&dl)[4]) {
        #pragma unroll
        for (int i = 0; i < 4; ++i) {
            dh[i] = *(const bf16x8*)(agh + i * 128);   // +16 pixels * 8
            dl[i] = *(const bf16x8*)(agl + i * 128);
        }
        agh += (size_t)4 * HW * 8;
        agl += (size_t)4 * HW * 8;
    };

    // 48-MFMA j-loop with j-pipelined B prefetch from L2 (proven R0-R3)
    auto step = [&](bf16x8 (&fah)[4], bf16x8 (&fal)[4]) {
        #pragma unroll
        for (int j = 0; j < 4; ++j) {
            size_t bnext = boff + ((j == 3) ? (size_t)(32768 - 384) : (size_t)128);
            bf16x8 nbh = *(const bf16x8*)(bgh + bnext);   // final (kt=15,j=3) load is
            bf16x8 nbl = *(const bf16x8*)(bgl + bnext);   // discarded (ws slack covers OOB)
            #pragma unroll
            for (int i = 0; i < 4; ++i) {
                acc[i][j] = __builtin_amdgcn_mfma_f32_16x16x32_bf16(fah[i], cbh, acc[i][j], 0, 0, 0);
                acc[i][j] = __builtin_amdgcn_mfma_f32_16x16x32_bf16(fah[i], cbl, acc[i][j], 0, 0, 0);
                acc[i][j] = __builtin_amdgcn_mfma_f32_16x16x32_bf16(fal[i], cbh, acc[i][j], 0, 0, 0);
            }
            cbh = nbh; cbl = nbl; boff = bnext;
        }
    };

    // ping-pong A across kt: named buffers, static indexing only
    bf16x8 hA[4], lA[4], hB[4], lB[4];
    ldA(hA, lA);                      // kt 0
    #pragma unroll 1
    for (int kt2 = 0; kt2 < 8; ++kt2) {
        ldA(hB, lB);                  // kt 2*kt2+1
        step(hA, lA);                 // compute kt 2*kt2
        if (kt2 < 7) ldA(hA, lA);     // kt 2*kt2+2
        step(hB, lB);                 // compute kt 2*kt2+1
    }

    // ---- epilogue: subtract centroid, square, e-reduce (16 lanes), exp, store
    float centv[4];
    #pragma unroll
    for (int j = 0; j < 4; ++j) {
        int cj = nb * 8 + wn * 4 + j;
        centv[j] = m_in[l16 * 64 + cj] / n_in[cj];
    }
    #pragma unroll
    for (int i = 0; i < 4; ++i) {
        #pragma unroll
        for (int j = 0; j < 4; ++j) {
            float s0 = acc[i][j][0] - centv[j]; s0 *= s0;
            float s1 = acc[i][j][1] - centv[j]; s1 *= s1;
            float s2 = acc[i][j][2] - centv[j]; s2 *= s2;
            float s3 = acc[i][j][3] - centv[j]; s3 *= s3;
            #pragma unroll
            for (int msk = 1; msk < 16; msk <<= 1) {
                s0 += __shfl_xor(s0, msk, 64);
                s1 += __shfl_xor(s1, msk, 64);
                s2 += __shfl_xor(s2, msk, 64);
                s3 += __shfl_xor(s3, msk, 64);
            }
            if (l16 == 0) {
                int cj = nb * 8 + wn * 4 + j;
                f4 o;
                o[0] = __expf(s0 * -3.125f);
                o[1] = __expf(s1 * -3.125f);
                o[2] = __expf(s2 * -3.125f);
                o[3] = __expf(s3 * -3.125f);
                size_t off = ((size_t)(bidx * 64 + cj)) * HW
                           + (size_t)(hw0 + wm * 64 + i * 16 + qd * 4);
                *(f4*)(out + off) = o;
            }
        }
    }
}

// ---------------------------------------------------------------------------
// Mid tier (R3 kernel, unchanged): direct global A loads + in-loop pack.
__global__ __launch_bounds__(256, 2) void duq_direct(
    const float* __restrict__ feat,
    const unsigned short* __restrict__ wh,
    const unsigned short* __restrict__ wl,
    const float* __restrict__ m_in,
    const float* __restrict__ n_in,
    float* __restrict__ out)
{
    const int t  = threadIdx.x;
    const int bx = blockIdx.x;
    const int kb = bx >> 3;
    const int nb = kb & 7;
    const int mb = (bx & 7) * 128 + (kb >> 3);
    const int bidx = mb >> 7;
    const int hw0  = (mb & 127) << 7;

    const int lane = t & 63;
    const int wv = t >> 6;
    const int wm = wv >> 1, wn = wv & 1;
    const int l16 = lane & 15, qd = lane >> 4;

    const float* apc = feat + (size_t)bidx * (FDIM * HW)
                     + (size_t)(qd * 8) * HW + (hw0 + wm * 64 + l16);

    const size_t bgoff = ((size_t)qd * 1024 + (size_t)(nb * 128 + wn * 64 + l16)) * 8;
    const unsigned short* bgh = wh + bgoff;
    const unsigned short* bgl = wl + bgoff;

    f32x4 acc[4][4] = {};

    bf16x8 cbh = *(const bf16x8*)(bgh);
    bf16x8 cbl = *(const bf16x8*)(bgl);
    size_t boff = 0;

    auto ldA = [&](float (&dst)[4][8]) {
        #pragma unroll
        for (int j = 0; j < 8; ++j) {
            const float* r = apc + (size_t)j * HW;
            #pragma unroll
            for (int i = 0; i < 4; ++i) dst[i][j] = r[i * 16];
        }
        apc += 32 * HW;
    };

    auto step = [&](float (&av)[4][8]) {
        bf16x8 fah[4], fal[4];
        #pragma unroll
        for (int i = 0; i < 4; ++i) {
            u32x4 hh = { pkhi(av[i][0], av[i][1]), pkhi(av[i][2], av[i][3]),
                         pkhi(av[i][4], av[i][5]), pkhi(av[i][6], av[i][7]) };
            u32x4 ll = { pklo(av[i][0], av[i][1]), pklo(av[i][2], av[i][3]),
                         pklo(av[i][4], av[i][5]), pklo(av[i][6], av[i][7]) };
            fah[i] = __builtin_bit_cast(bf16x8, hh);
            fal[i] = __builtin_bit_cast(bf16x8, ll);
        }
        #pragma unroll
        for (int j = 0; j < 4; ++j) {
            size_t bnext = boff + ((j == 3) ? (size_t)(32768 - 384) : (size_t)128);
            bf16x8 nbh = *(const bf16x8*)(bgh + bnext);
            bf16x8 nbl = *(const bf16x8*)(bgl + bnext);
            #pragma unroll
            for (int i = 0; i < 4; ++i) {
                acc[i][j] = __builtin_amdgcn_mfma_f32_16x16x32_bf16(fah[i], cbh, acc[i][j], 0, 0, 0);
                acc[i][j] = __builtin_amdgcn_mfma_f32_16x16x32_bf16(fah[i], cbl, acc[i][j], 0, 0, 0);
                acc[i][j] = __builtin_amdgcn_mfma_f32_16x16x32_bf16(fal[i], cbh, acc[i][j], 0, 0, 0);
            }
            cbh = nbh; cbl = nbl; boff = bnext;
        }
    };

    float avA[4][8], avB[4][8];
    ldA(avA);
    #pragma unroll 1
    for (int kt2 = 0; kt2 < 8; ++kt2) {
        ldA(avB);
        step(avA);
        if (kt2 < 7) ldA(avA);
        step(avB);
    }

    float centv[4];
    #pragma unroll
    for (int j = 0; j < 4; ++j) {
        int cj = nb * 8 + wn * 4 + j;
        centv[j] = m_in[l16 * 64 + cj] / n_in[cj];
    }
    #pragma unroll
    for (int i = 0; i < 4; ++i) {
        #pragma unroll
        for (int j = 0; j < 4; ++j) {
            float s0 = acc[i][j][0] - centv[j]; s0 *= s0;
            float s1 = acc[i][j][1] - centv[j]; s1 *= s1;
            float s2 = acc[i][j][2] - centv[j]; s2 *= s2;
            float s3 = acc[i][j][3] - centv[j]; s3 *= s3;
            #pragma unroll
            for (int msk = 1; msk < 16; msk <<= 1) {
                s0 += __shfl_xor(s0, msk, 64);
                s1 += __shfl_xor(s1, msk, 64);
                s2 += __shfl_xor(s2, msk, 64);
                s3 += __shfl_xor(s3, msk, 64);
            }
            if (l16 == 0) {
                int cj = nb * 8 + wn * 4 + j;
                f4 o;
                o[0] = __expf(s0 * -3.125f);
                o[1] = __expf(s1 * -3.125f);
                o[2] = __expf(s2 * -3.125f);
                o[3] = __expf(s3 * -3.125f);
                size_t off = ((size_t)(bidx * 64 + cj)) * HW
                           + (size_t)(hw0 + wm * 64 + i * 16 + qd * 4);
                *(f4*)(out + off) = o;
            }
        }
    }
}

// ---------------------------------------------------------------------------
// Fallback (LDS-staged A and B) if ws is too small for any precompute.
__global__ __launch_bounds__(256) void duq_fallback(
    const float* __restrict__ feat, const float* __restrict__ wts,
    const float* __restrict__ m_in, const float* __restrict__ n_in,
    float* __restrict__ out)
{
    __shared__ __align__(16) unsigned short Ah[128 * 40];
    __shared__ __align__(16) unsigned short Al[128 * 40];
    __shared__ __align__(16) unsigned short Bh[128 * 40];
    __shared__ __align__(16) unsigned short Bl[128 * 40];

    const int t  = threadIdx.x;
    const int bx = blockIdx.x;
    const int nb = bx & 7;
    const int mb = bx >> 3;
    const int bidx = mb >> 7;
    const int hw0  = (mb & 127) << 7;

    const int fb = t & 7;
    const int pb = t >> 3;
    const float* ap = feat + (size_t)bidx * (FDIM * HW) + (size_t)(fb * 4) * HW + (hw0 + pb * 4);

    const int bn  = t >> 1;
    const int bh_ = t & 1;
    const int ng  = nb * 128 + bn;
    const float* bp = wts + (size_t)((ng & 15) * 64 + (ng >> 4)) * FDIM + bh_ * 16;

    unsigned short* awH = &Ah[(pb * 4) * 40 + fb * 4];
    unsigned short* awL = &Al[(pb * 4) * 40 + fb * 4];
    unsigned short* bwH = &Bh[bn * 40 + bh_ * 16];
    unsigned short* bwL = &Bl[bn * 40 + bh_ * 16];

    const int lane = t & 63;
    const int wv = t >> 6;
    const int wm = wv >> 1, wn = wv & 1;
    const int l16 = lane & 15, qd = lane >> 4;

    const unsigned short* arH = &Ah[(wm * 64 + l16) * 40 + qd * 8];
    const unsigned short* arL = &Al[(wm * 64 + l16) * 40 + qd * 8];
    const unsigned short* brH = &Bh[(wn * 64 + l16) * 40 + qd * 8];
    const unsigned short* brL = &Bl[(wn * 64 + l16) * 40 + qd * 8];

    f32x4 acc[4][4] = {};

    f4 av[4], bv[4];
    #pragma unroll
    for (int i = 0; i < 4; ++i) av[i] = *(const f4*)(ap + (size_t)i * HW);
    #pragma unroll
    for (int q = 0; q < 4; ++q) bv[q] = *(const f4*)(bp + q * 4);

    for (int kt = 0; kt < 16; ++kt) {
        __syncthreads();
        #pragma unroll
        for (int j = 0; j < 4; ++j) {
            float a0 = av[0][j], a1 = av[1][j], a2 = av[2][j], a3 = av[3][j];
            u32x2 h, l;
            h[0] = pkhi(a0, a1); h[1] = pkhi(a2, a3);
            l[0] = pklo(a0, a1); l[1] = pklo(a2, a3);
            *(u32x2*)(awH + j * 40) = h;
            *(u32x2*)(awL + j * 40) = l;
        }
        {
            u32x4 h0 = { pkhi(bv[0][0], bv[0][1]), pkhi(bv[0][2], bv[0][3]),
                         pkhi(bv[1][0], bv[1][1]), pkhi(bv[1][2], bv[1][3]) };
            u32x4 h1 = { pkhi(bv[2][0], bv[2][1]), pkhi(bv[2][2], bv[2][3]),
                         pkhi(bv[3][0], bv[3][1]), pkhi(bv[3][2], bv[3][3]) };
            u32x4 l0 = { pklo(bv[0][0], bv[0][1]), pklo(bv[0][2], bv[0][3]),
                         pklo(bv[1][0], bv[1][1]), pklo(bv[1][2], bv[1][3]) };
            u32x4 l1 = { pklo(bv[2][0], bv[2][1]), pklo(bv[2][2], bv[2][3]),
                         pklo(bv[3][0], bv[3][1]), pklo(bv[3][2], bv[3][3]) };
            *(u32x4*)(bwH)     = h0;  *(u32x4*)(bwH + 8) = h1;
            *(u32x4*)(bwL)     = l0;  *(u32x4*)(bwL + 8) = l1;
        }
        __syncthreads();

        if (kt < 15) {
            ap += 32 * HW;
            bp += 32;
            #pragma unroll
            for (int i = 0; i < 4; ++i) av[i] = *(const f4*)(ap + (size_t)i * HW);
            #pragma unroll
            for (int q = 0; q < 4; ++q) bv[q] = *(const f4*)(bp + q * 4);
        }

        bf16x8 fah[4], fal[4];
        #pragma unroll
        for (int i = 0; i < 4; ++i) {
            fah[i] = *(const bf16x8*)(arH + i * 640);
            fal[i] = *(const bf16x8*)(arL + i * 640);
        }
        #pragma unroll
        for (int j = 0; j < 4; ++j) {
            bf16x8 fbh = *(const bf16x8*)(brH + j * 640);
            bf16x8 fbl = *(const bf16x8*)(brL + j * 640);
            #pragma unroll
            for (int i = 0; i < 4; ++i) {
                acc[i][j] = __builtin_amdgcn_mfma_f32_16x16x32_bf16(fah[i], fbh, acc[i][j], 0, 0, 0);
                acc[i][j] = __builtin_amdgcn_mfma_f32_16x16x32_bf16(fah[i], fbl, acc[i][j], 0, 0, 0);
                acc[i][j] = __builtin_amdgcn_mfma_f32_16x16x32_bf16(fal[i], fbh, acc[i][j], 0, 0, 0);
            }
        }
    }

    float centv[4];
    #pragma unroll
    for (int j = 0; j < 4; ++j) {
        int cj = nb * 8 + wn * 4 + j;
        centv[j] = m_in[l16 * 64 + cj] / n_in[cj];
    }
    #pragma unroll
    for (int i = 0; i < 4; ++i) {
        #pragma unroll
        for (int j = 0; j < 4; ++j) {
            float s0 = acc[i][j][0] - centv[j]; s0 *= s0;
            float s1 = acc[i][j][1] - centv[j]; s1 *= s1;
            float s2 = acc[i][j][2] - centv[j]; s2 *= s2;
            float s3 = acc[i][j][3] - centv[j]; s3 *= s3;
            #pragma unroll
            for (int msk = 1; msk < 16; msk <<= 1) {
                s0 += __shfl_xor(s0, msk, 64);
                s1 += __shfl_xor(s1, msk, 64);
                s2 += __shfl_xor(s2, msk, 64);
                s3 += __shfl_xor(s3, msk, 64);
            }
            if (l16 == 0) {
                int cj = nb * 8 + wn * 4 + j;
                f4 o;
                o[0] = __expf(s0 * -3.125f);
                o[1] = __expf(s1 * -3.125f);
                o[2] = __expf(s2 * -3.125f);
                o[3] = __expf(s3 * -3.125f);
                size_t off = ((size_t)(bidx * 64 + cj)) * HW
                           + (size_t)(hw0 + wm * 64 + i * 16 + qd * 4);
                *(f4*)(out + off) = o;
            }
        }
    }
}

extern "C" void kernel_launch(void* const* d_in, const int* in_sizes, int n_in,
                              void* d_out, int out_size, void* d_ws, size_t ws_size,
                              hipStream_t stream) {
    const float* feat = (const float*)d_in[0];
    const float* wts  = (const float*)d_in[1];
    const float* mbuf = (const float*)d_in[2];
    const float* nbuf = (const float*)d_in[3];
    float* out = (float*)d_out;

    // ws layout: [wh 1MB][wl 1MB][slack 128KB][ah 128MB][al 128MB]
    const size_t WS_MID = (size_t)(2 * 1024 * 1024 + 128 * 1024);
    const size_t WS_BIG = WS_MID + (size_t)256 * 1024 * 1024;

    if (ws_size >= WS_MID) {
        unsigned short* wh = (unsigned short*)d_ws;
        unsigned short* wl = wh + 512 * 1024;   // 1 MB in
        conv_w<<<dim3(256), dim3(256), 0, stream>>>(wts, wh, wl);
        if (ws_size >= WS_BIG) {
            unsigned short* ah = wh + WS_MID / 2;                   // 2MB+128KB in
            unsigned short* al = ah + (size_t)64 * 1024 * 1024;     // +128 MB
            conv_a<<<dim3(32768), dim3(256), 0, stream>>>(feat, ah, al);
            duq_pre<<<dim3(1024 * 8), dim3(256), 0, stream>>>(ah, al, wh, wl, mbuf, nbuf, out);
        } else {
            duq_direct<<<dim3(1024 * 8), dim3(256), 0, stream>>>(feat, wh, wl, mbuf, nbuf, out);
        }
    } else {
        duq_fallback<<<dim3(1024 * 8), dim3(256), 0, stream>>>(feat, wts, mbuf, nbuf, out);
    }
}

// Round 5
// 676.003 us; speedup vs baseline: 1.1250x; 1.1250x over previous
//
#include <hip/hip_runtime.h>

typedef __attribute__((ext_vector_type(8))) short bf16x8;   // 8 bf16 = 4 VGPRs (MFMA A/B frag)
typedef __attribute__((ext_vector_type(4))) float f32x4;    // MFMA C/D frag
typedef __attribute__((ext_vector_type(4))) float f4;
typedef __attribute__((ext_vector_type(2))) unsigned int u32x2;
typedef __attribute__((ext_vector_type(4))) unsigned int u32x4;

#define HW   16384   // 128*128
#define FDIM 512

// pack bf16(trunc) of a (low 16) and b (high 16) in one v_perm_b32
__device__ __forceinline__ unsigned pkhi(float a, float b) {
    return __builtin_amdgcn_perm(__builtin_bit_cast(unsigned int, b),
                                 __builtin_bit_cast(unsigned int, a),
                                 0x07060302u);
}
__device__ __forceinline__ float trhi(float a) {
    return __builtin_bit_cast(float, __builtin_bit_cast(unsigned int, a) & 0xFFFF0000u);
}
__device__ __forceinline__ unsigned pklo(float a, float b) {
    return pkhi(a - trhi(a), b - trhi(b));
}

// ---------------------------------------------------------------------------
// Prologue: convert W[e,c,f] fp32 -> bf16 hi/lo in d_ws, n-reordered
// (n=c*16+e), MFMA B-frag order: W'[kchunk 0..63][n 0..1023][8 bf16].
__global__ __launch_bounds__(256) void conv_w(const float* __restrict__ wts,
                                              unsigned short* __restrict__ wh,
                                              unsigned short* __restrict__ wl) {
    const int tid = blockIdx.x * 256 + threadIdx.x;   // 65536 threads
    const int n  = tid & 1023;
    const int kc = tid >> 10;                         // k-chunk 0..63
    const float* src = wts + (size_t)((n & 15) * 64 + (n >> 4)) * FDIM + kc * 8;
    f4 a = *(const f4*)src, b = *(const f4*)(src + 4);
    u32x4 h = { pkhi(a[0], a[1]), pkhi(a[2], a[3]), pkhi(b[0], b[1]), pkhi(b[2], b[3]) };
    u32x4 l = { pklo(a[0], a[1]), pklo(a[2], a[3]), pklo(b[0], b[1]), pklo(b[2], b[3]) };
    size_t off = ((size_t)kc * 1024 + n) * 8;
    *(u32x4*)(wh + off) = h;    // 16 B per thread, consecutive n -> coalesced
    *(u32x4*)(wl + off) = l;
}

// ---------------------------------------------------------------------------
// Main (R5): fused wide-N tile. R4 post-mortem: conv_a's 512 MB HBM round
// trip (~125 us) > its savings; and MfmaUtil stalled at 48% from 1-j-deep B
// prefetch (58 cyc cover vs ~200 cyc L2). Fix both IN one kernel:
//   - block = 128 pixels x 256 n (2 old nb): A loaded from feat + packed ONCE
//     per kt per block, feeding 96 MFMAs (pack VALU ~20% of MFMA cycles,
//     vs ~100% in R3). No conv_a, no A' traffic.
//   - B prefetch 3 j-steps ahead via 4 rotating slots (8%4==0 so slot indices
//     are kt-invariant -> fully static after unroll): ~174 cyc cover/wave.
//   - XCD swizzle (proven R2): 4 nb2-siblings of an mb dispatch-adjacent on
//     one XCD -> A panel read once per XCD L2.
// acc 128 AGPR + ~100 arch VGPR ~= 230 total -> 2 waves/SIMD, no spill.
// Numerics: identical 3-term hi/lo split, identical accumulation order.
__global__ __launch_bounds__(256, 2) void duq_fused(
    const float* __restrict__ feat,          // [8,512,128,128]
    const unsigned short* __restrict__ wh,   // [64][1024][8] bf16 hi
    const unsigned short* __restrict__ wl,   // bf16 lo
    const float* __restrict__ m_in,          // [16,64]
    const float* __restrict__ n_in,          // [64]
    float* __restrict__ out)                 // [8,64,128,128]
{
    const int t  = threadIdx.x;
    const int bx = blockIdx.x;                // 4096 blocks
    // (bx&7) = XCD id; kb&3 = nb2 (fastest -> 4 siblings adjacent on XCD)
    const int kb  = bx >> 3;
    const int nb2 = kb & 3;                   // N block: 1024/256
    const int mb  = (bx & 7) * 128 + (kb >> 2);
    const int bidx = mb >> 7;
    const int hw0  = (mb & 127) << 7;

    const int lane = t & 63;
    const int wv = t >> 6;
    const int wm = wv >> 1, wn = wv & 1;      // 2x2 waves: 64 px x 128 n each
    const int l16 = lane & 15, qd = lane >> 4;

    // A: lane's pixel row = hw0 + wm*64 + l16 (+i*16), k = kt*32 + qd*8 + jk
    const float* apc = feat + (size_t)bidx * (FDIM * HW)
                     + (size_t)(qd * 8) * HW + (hw0 + wm * 64 + l16);

    // B frag (kt,j): 16 B at bgh + kt*32768 + j*128 (shorts), j = 0..7,
    // n = nb2*256 + wn*128 + j*16 + l16
    const size_t bgoff = ((size_t)qd * 1024 + (size_t)(nb2 * 256 + wn * 128 + l16)) * 8;
    const unsigned short* bgh = wh + bgoff;
    const unsigned short* bgl = wl + bgoff;

    f32x4 acc[4][8] = {};

    // B slot file: 4 slots, use j&3, load (j+3)&3 (3-ahead). Period 4 divides
    // 8 j's per kt -> slot mapping identical every kt (static indices).
    bf16x8 sh[4], sl[4];
    sh[0] = *(const bf16x8*)(bgh);        sl[0] = *(const bf16x8*)(bgl);
    sh[1] = *(const bf16x8*)(bgh + 128);  sl[1] = *(const bf16x8*)(bgl + 128);
    sh[2] = *(const bf16x8*)(bgh + 256);  sl[2] = *(const bf16x8*)(bgl + 256);
    const unsigned short* bkh = bgh;      // advances 32768 shorts per kt
    const unsigned short* bkl = bgl;

    // issue one kt's 32 A loads (4 i x 8 jk)
    auto ldA = [&](float (&dst)[4][8]) {
        #pragma unroll
        for (int jk = 0; jk < 8; ++jk) {
            const float* r = apc + (size_t)jk * HW;
            #pragma unroll
            for (int i = 0; i < 4; ++i) dst[i][jk] = r[i * 16];
        }
        apc += 32 * HW;
    };

    // pack one kt's A to hi/lo frags, run 96 MFMAs with 3-ahead B prefetch
    auto step = [&](float (&av)[4][8]) {
        bf16x8 fah[4], fal[4];
        #pragma unroll
        for (int i = 0; i < 4; ++i) {
            u32x4 hh = { pkhi(av[i][0], av[i][1]), pkhi(av[i][2], av[i][3]),
                         pkhi(av[i][4], av[i][5]), pkhi(av[i][6], av[i][7]) };
            u32x4 ll = { pklo(av[i][0], av[i][1]), pklo(av[i][2], av[i][3]),
                         pklo(av[i][4], av[i][5]), pklo(av[i][6], av[i][7]) };
            fah[i] = __builtin_bit_cast(bf16x8, hh);
            fal[i] = __builtin_bit_cast(bf16x8, ll);
        }
        #pragma unroll
        for (int j = 0; j < 8; ++j) {
            // prefetch B for g+3 (j<5: this kt at (j+3)*128; else next kt).
            // Final kt's tail loads land in ws slack / wl region - discarded.
            const int ls = (j + 3) & 3;
            const size_t poff = (j < 5) ? (size_t)((j + 3) * 128)
                                        : (size_t)(32768 + (j - 5) * 128);
            sh[ls] = *(const bf16x8*)(bkh + poff);
            sl[ls] = *(const bf16x8*)(bkl + poff);
            const int us = j & 3;
            #pragma unroll
            for (int i = 0; i < 4; ++i) {
                acc[i][j] = __builtin_amdgcn_mfma_f32_16x16x32_bf16(fah[i], sh[us], acc[i][j], 0, 0, 0);
                acc[i][j] = __builtin_amdgcn_mfma_f32_16x16x32_bf16(fah[i], sl[us], acc[i][j], 0, 0, 0);
                acc[i][j] = __builtin_amdgcn_mfma_f32_16x16x32_bf16(fal[i], sh[us], acc[i][j], 0, 0, 0);
            }
        }
        bkh += 32768; bkl += 32768;
    };

    // ping-pong A across kt (named buffers, static indexing only)
    float avA[4][8], avB[4][8];
    ldA(avA);                         // kt 0
    #pragma unroll 1
    for (int kt2 = 0; kt2 < 8; ++kt2) {
        ldA(avB);                     // kt 2*kt2+1
        step(avA);                    // compute kt 2*kt2
        if (kt2 < 7) ldA(avA);        // kt 2*kt2+2
        step(avB);                    // compute kt 2*kt2+1
    }

    // ---- epilogue: subtract centroid, square, e-reduce (16 lanes), exp, store
    #pragma unroll
    for (int i = 0; i < 4; ++i) {
        #pragma unroll
        for (int j = 0; j < 8; ++j) {
            const int cj = nb2 * 16 + wn * 8 + j;
            const float cent = m_in[l16 * 64 + cj] / n_in[cj];
            float s0 = acc[i][j][0] - cent; s0 *= s0;
            float s1 = acc[i][j][1] - cent; s1 *= s1;
            float s2 = acc[i][j][2] - cent; s2 *= s2;
            float s3 = acc[i][j][3] - cent; s3 *= s3;
            #pragma unroll
            for (int msk = 1; msk < 16; msk <<= 1) {
                s0 += __shfl_xor(s0, msk, 64);
                s1 += __shfl_xor(s1, msk, 64);
                s2 += __shfl_xor(s2, msk, 64);
                s3 += __shfl_xor(s3, msk, 64);
            }
            if (l16 == 0) {
                f4 o;
                o[0] = __expf(s0 * -3.125f);
                o[1] = __expf(s1 * -3.125f);
                o[2] = __expf(s2 * -3.125f);
                o[3] = __expf(s3 * -3.125f);
                size_t off = ((size_t)(bidx * 64 + cj)) * HW
                           + (size_t)(hw0 + wm * 64 + i * 16 + qd * 4);
                *(f4*)(out + off) = o;
            }
        }
    }
}

// ---------------------------------------------------------------------------
// Fallback (LDS-staged A and B) if ws is too small for W' precompute.
__global__ __launch_bounds__(256) void duq_fallback(
    const float* __restrict__ feat, const float* __restrict__ wts,
    const float* __restrict__ m_in, const float* __restrict__ n_in,
    float* __restrict__ out)
{
    __shared__ __align__(16) unsigned short Ah[128 * 40];
    __shared__ __align__(16) unsigned short Al[128 * 40];
    __shared__ __align__(16) unsigned short Bh[128 * 40];
    __shared__ __align__(16) unsigned short Bl[128 * 40];

    const int t  = threadIdx.x;
    const int bx = blockIdx.x;
    const int nb = bx & 7;
    const int mb = bx >> 3;
    const int bidx = mb >> 7;
    const int hw0  = (mb & 127) << 7;

    const int fb = t & 7;
    const int pb = t >> 3;
    const float* ap = feat + (size_t)bidx * (FDIM * HW) + (size_t)(fb * 4) * HW + (hw0 + pb * 4);

    const int bn  = t >> 1;
    const int bh_ = t & 1;
    const int ng  = nb * 128 + bn;
    const float* bp = wts + (size_t)((ng & 15) * 64 + (ng >> 4)) * FDIM + bh_ * 16;

    unsigned short* awH = &Ah[(pb * 4) * 40 + fb * 4];
    unsigned short* awL = &Al[(pb * 4) * 40 + fb * 4];
    unsigned short* bwH = &Bh[bn * 40 + bh_ * 16];
    unsigned short* bwL = &Bl[bn * 40 + bh_ * 16];

    const int lane = t & 63;
    const int wv = t >> 6;
    const int wm = wv >> 1, wn = wv & 1;
    const int l16 = lane & 15, qd = lane >> 4;

    const unsigned short* arH = &Ah[(wm * 64 + l16) * 40 + qd * 8];
    const unsigned short* arL = &Al[(wm * 64 + l16) * 40 + qd * 8];
    const unsigned short* brH = &Bh[(wn * 64 + l16) * 40 + qd * 8];
    const unsigned short* brL = &Bl[(wn * 64 + l16) * 40 + qd * 8];

    f32x4 acc[4][4] = {};

    f4 av[4], bv[4];
    #pragma unroll
    for (int i = 0; i < 4; ++i) av[i] = *(const f4*)(ap + (size_t)i * HW);
    #pragma unroll
    for (int q = 0; q < 4; ++q) bv[q] = *(const f4*)(bp + q * 4);

    for (int kt = 0; kt < 16; ++kt) {
        __syncthreads();
        #pragma unroll
        for (int j = 0; j < 4; ++j) {
            float a0 = av[0][j], a1 = av[1][j], a2 = av[2][j], a3 = av[3][j];
            u32x2 h, l;
            h[0] = pkhi(a0, a1); h[1] = pkhi(a2, a3);
            l[0] = pklo(a0, a1); l[1] = pklo(a2, a3);
            *(u32x2*)(awH + j * 40) = h;
            *(u32x2*)(awL + j * 40) = l;
        }
        {
            u32x4 h0 = { pkhi(bv[0][0], bv[0][1]), pkhi(bv[0][2], bv[0][3]),
                         pkhi(bv[1][0], bv[1][1]), pkhi(bv[1][2], bv[1][3]) };
            u32x4 h1 = { pkhi(bv[2][0], bv[2][1]), pkhi(bv[2][2], bv[2][3]),
                         pkhi(bv[3][0], bv[3][1]), pkhi(bv[3][2], bv[3][3]) };
            u32x4 l0 = { pklo(bv[0][0], bv[0][1]), pklo(bv[0][2], bv[0][3]),
                         pklo(bv[1][0], bv[1][1]), pklo(bv[1][2], bv[1][3]) };
            u32x4 l1 = { pklo(bv[2][0], bv[2][1]), pklo(bv[2][2], bv[2][3]),
                         pklo(bv[3][0], bv[3][1]), pklo(bv[3][2], bv[3][3]) };
            *(u32x4*)(bwH)     = h0;  *(u32x4*)(bwH + 8) = h1;
            *(u32x4*)(bwL)     = l0;  *(u32x4*)(bwL + 8) = l1;
        }
        __syncthreads();

        if (kt < 15) {
            ap += 32 * HW;
            bp += 32;
            #pragma unroll
            for (int i = 0; i < 4; ++i) av[i] = *(const f4*)(ap + (size_t)i * HW);
            #pragma unroll
            for (int q = 0; q < 4; ++q) bv[q] = *(const f4*)(bp + q * 4);
        }

        bf16x8 fah[4], fal[4];
        #pragma unroll
        for (int i = 0; i < 4; ++i) {
            fah[i] = *(const bf16x8*)(arH + i * 640);
            fal[i] = *(const bf16x8*)(arL + i * 640);
        }
        #pragma unroll
        for (int j = 0; j < 4; ++j) {
            bf16x8 fbh = *(const bf16x8*)(brH + j * 640);
            bf16x8 fbl = *(const bf16x8*)(brL + j * 640);
            #pragma unroll
            for (int i = 0; i < 4; ++i) {
                acc[i][j] = __builtin_amdgcn_mfma_f32_16x16x32_bf16(fah[i], fbh, acc[i][j], 0, 0, 0);
                acc[i][j] = __builtin_amdgcn_mfma_f32_16x16x32_bf16(fah[i], fbl, acc[i][j], 0, 0, 0);
                acc[i][j] = __builtin_amdgcn_mfma_f32_16x16x32_bf16(fal[i], fbh, acc[i][j], 0, 0, 0);
            }
        }
    }

    float centv[4];
    #pragma unroll
    for (int j = 0; j < 4; ++j) {
        int cj = nb * 8 + wn * 4 + j;
        centv[j] = m_in[l16 * 64 + cj] / n_in[cj];
    }
    #pragma unroll
    for (int i = 0; i < 4; ++i) {
        #pragma unroll
        for (int j = 0; j < 4; ++j) {
            float s0 = acc[i][j][0] - centv[j]; s0 *= s0;
            float s1 = acc[i][j][1] - centv[j]; s1 *= s1;
            float s2 = acc[i][j][2] - centv[j]; s2 *= s2;
            float s3 = acc[i][j][3] - centv[j]; s3 *= s3;
            #pragma unroll
            for (int msk = 1; msk < 16; msk <<= 1) {
                s0 += __shfl_xor(s0, msk, 64);
                s1 += __shfl_xor(s1, msk, 64);
                s2 += __shfl_xor(s2, msk, 64);
                s3 += __shfl_xor(s3, msk, 64);
            }
            if (l16 == 0) {
                int cj = nb * 8 + wn * 4 + j;
                f4 o;
                o[0] = __expf(s0 * -3.125f);
                o[1] = __expf(s1 * -3.125f);
                o[2] = __expf(s2 * -3.125f);
                o[3] = __expf(s3 * -3.125f);
                size_t off = ((size_t)(bidx * 64 + cj)) * HW
                           + (size_t)(hw0 + wm * 64 + i * 16 + qd * 4);
                *(f4*)(out + off) = o;
            }
        }
    }
}

extern "C" void kernel_launch(void* const* d_in, const int* in_sizes, int n_in,
                              void* d_out, int out_size, void* d_ws, size_t ws_size,
                              hipStream_t stream) {
    const float* feat = (const float*)d_in[0];
    const float* wts  = (const float*)d_in[1];
    const float* mbuf = (const float*)d_in[2];
    const float* nbuf = (const float*)d_in[3];
    float* out = (float*)d_out;

    // W' needs 2 MB + 128 KB slack (discarded tail prefetch reads past wl end)
    if (ws_size >= (size_t)(2 * 1024 * 1024 + 128 * 1024)) {
        unsigned short* wh = (unsigned short*)d_ws;
        unsigned short* wl = wh + 512 * 1024;   // 1 MB in
        conv_w<<<dim3(256), dim3(256), 0, stream>>>(wts, wh, wl);
        duq_fused<<<dim3(4096), dim3(256), 0, stream>>>(feat, wh, wl, mbuf, nbuf, out);
    } else {
        duq_fallback<<<dim3(1024 * 8), dim3(256), 0, stream>>>(feat, wts, mbuf, nbuf, out);
    }
}